// Round 9
// baseline (483.621 us; speedup 1.0000x reference)
//
#include <hip/hip_runtime.h>
#include <hip/hip_bf16.h>

// B=32, S=577, H=1024, NH=16, DH=64. fp32 inputs / fp32 OUTPUT.
// Round 15: qkv traffic attack (schedule restructures are a proven dead end
// on this shape — R10-R13). (1) Q/K epilogue LDS-transpose: stage 64-row
// half-tiles in smem[64][136] (padded vs bank aliasing), store full-64B-line
// bf16x8 runs -> kills partial-line write amplification (WRITE 172->~125MB)
// and its RMW fetch. (2) slab height 8->12 m-tiles (3MB X + W tile fits XCD
// L2): W refetch 114->78MB. Same slab for out_gemm. Main loops, flash_attn
// (R14 4-q-tile), cvt_all unchanged.

typedef __bf16 bf16_t;
typedef __bf16 bf16x8 __attribute__((ext_vector_type(8)));
typedef __bf16 bf16x4 __attribute__((ext_vector_type(4)));
typedef float f32x4 __attribute__((ext_vector_type(4)));

#define B_   32
#define S_   577
#define SP   608
#define H_   1024
#define NH_  16
#define DH_  64
#define M_   (B_ * S_)    // 18464

typedef __attribute__((address_space(3))) unsigned int lds_u32;
typedef const __attribute__((address_space(1))) unsigned int glb_u32;
#define STAGE16(gp, lp) __builtin_amdgcn_global_load_lds((glb_u32*)(gp), (lds_u32*)(lp), 16, 0, 0)
#define MFMA_BF16 __builtin_amdgcn_mfma_f32_16x16x32_bf16

__device__ __forceinline__ bf16x8 load8(const bf16_t* p) {
    return *reinterpret_cast<const bf16x8*>(p);
}
__device__ __forceinline__ bf16x8 load8f(const float* p) {
    f32x4 a = *reinterpret_cast<const f32x4*>(p);
    f32x4 b = *reinterpret_cast<const f32x4*>(p + 4);
    bf16x8 r;
    r[0] = (bf16_t)a[0]; r[1] = (bf16_t)a[1]; r[2] = (bf16_t)a[2]; r[3] = (bf16_t)a[3];
    r[4] = (bf16_t)b[0]; r[5] = (bf16_t)b[1]; r[6] = (bf16_t)b[2]; r[7] = (bf16_t)b[3];
    return r;
}

// ---------------- fused fp32 -> bf16 convert (X + 4 weights, one launch) ----
__global__ __launch_bounds__(256) void cvt_all(
    const float* __restrict__ x,
    const float* __restrict__ w0, const float* __restrict__ w1,
    const float* __restrict__ w2, const float* __restrict__ w3,
    bf16_t* __restrict__ xdst, bf16_t* __restrict__ wdst, int xn8)
{
    int i = blockIdx.x * blockDim.x + threadIdx.x;
    const int stride = gridDim.x * blockDim.x;
    const int total = xn8 + 4 * (1 << 17);
    for (; i < total; i += stride) {
        if (i < xn8) {
            *reinterpret_cast<bf16x8*>(xdst + (size_t)i * 8) = load8f(x + (size_t)i * 8);
        } else {
            const int j = i - xn8;
            const int which = j >> 17, off = j & ((1 << 17) - 1);
            const float* s = (which == 0) ? w0 : (which == 1) ? w1 : (which == 2) ? w2 : w3;
            *reinterpret_cast<bf16x8*>(wdst + (size_t)j * 8) = load8f(s + (size_t)off * 8);
        }
    }
}

// ---- R9 1-phase m97 main loop (best measured for this shape) ----
#define GEMM_MAINLOOP(SWAP)                                                      \
    for (int k0 = 0; k0 < H_; k0 += 32) {                                        \
        STAGE16(pA0 + k0, lA0);                                                  \
        STAGE16(pA1 + k0, lA1);                                                  \
        STAGE16(pB0 + k0, lB0);                                                  \
        STAGE16(pB1 + k0, lB1);                                                  \
        __syncthreads();                                                         \
        bf16x8 af[4], bfv[4];                                                    \
        _Pragma("unroll")                                                        \
        for (int tt = 0; tt < 4; ++tt) {                                         \
            af[tt]  = load8(sA + (wm * 64 + tt * 16 + l16) * 32 + quad * 8);     \
            bfv[tt] = load8(sB + (wn * 64 + tt * 16 + l16) * 32 + quad * 8);     \
        }                                                                        \
        _Pragma("unroll")                                                        \
        for (int i = 0; i < 4; ++i)                                              \
            _Pragma("unroll")                                                    \
            for (int j = 0; j < 4; ++j)                                          \
                acc[i][j] = (SWAP)                                               \
                    ? MFMA_BF16(bfv[j], af[i], acc[i][j], 0, 0, 0)               \
                    : MFMA_BF16(af[i], bfv[j], acc[i][j], 0, 0, 0);              \
        __syncthreads();                                                         \
    }

// ---------------- fused QKV projection ----------------
// 1-D grid 3480 = 145 m-tiles x 24 n-tiles; 12-m-tile slabs (3MB X, L2-fit
// with W tile), m-fast within slab; contiguous 435-work chunk per XCD.
__global__ __launch_bounds__(256) void qkv_gemm(
    const bf16_t* __restrict__ Xb,
    const bf16_t* __restrict__ Wqb, const bf16_t* __restrict__ Wkb, const bf16_t* __restrict__ Wvb,
    const float* __restrict__ bq, const float* __restrict__ bk, const float* __restrict__ bv,
    bf16_t* __restrict__ Qb, bf16_t* __restrict__ Kb, bf16_t* __restrict__ VTb)
{
    __shared__ bf16_t smem[8704];          // main: 8192 (A|B); epilogue: [64][136]
    bf16_t* sA = smem;
    bf16_t* sB = smem + 4096;
    const int tid  = threadIdx.x;
    const int w    = tid >> 6, lane = tid & 63;
    const int quad = lane >> 4, l16 = lane & 15;
    const int wm = w & 1, wn = w >> 1;

    const int t    = (blockIdx.x & 7) * 435 + (blockIdx.x >> 3);  // bijective, 3480%8==0
    const int slab = t / 288;                                     // 12 m-tiles x 24 n
    const int rem  = t - slab * 288;
    int mt, nt;
    if (slab < 12) { nt = rem / 12; mt = slab * 12 + (rem - nt * 12); }
    else           { nt = rem;      mt = 144; }                   // last partial slab
    const int m0 = mt * 128, n0 = nt * 128;

    const int which = n0 >> 10;            // 128-tile never straddles a weight boundary
    const int nrel0 = n0 & 1023;
    const bf16_t* Wb   = (which == 0) ? Wqb : (which == 1) ? Wkb : Wvb;
    const float*  bias = (which == 0) ? bq  : (which == 1) ? bk  : bv;
    const float   oscale = (which == 0) ? 0.125f : 1.0f;

    const int f0 = tid, f1 = 256 + tid;
    const int rA0 = f0 >> 2, cA0 = (f0 & 3) * 8;
    const int rA1 = f1 >> 2, cA1 = (f1 & 3) * 8;
    int ga0 = m0 + rA0; if (ga0 > M_ - 1) ga0 = M_ - 1;
    int ga1 = m0 + rA1; if (ga1 > M_ - 1) ga1 = M_ - 1;
    const bf16_t* pA0 = Xb + (size_t)ga0 * H_ + cA0;
    const bf16_t* pA1 = Xb + (size_t)ga1 * H_ + cA1;
    const bf16_t* pB0 = Wb + (size_t)(nrel0 + rA0) * H_ + cA0;
    const bf16_t* pB1 = Wb + (size_t)(nrel0 + rA1) * H_ + cA1;
    bf16_t* lA0 = sA + w * 512;            // wave-uniform bases (+lane*16B by HW)
    bf16_t* lA1 = sA + 2048 + w * 512;
    bf16_t* lB0 = sB + w * 512;
    bf16_t* lB1 = sB + 2048 + w * 512;

    f32x4 acc[4][4] = {};
    if (which != 2) {
        GEMM_MAINLOOP(1)
        // swapped: m = m0+wm*64+i*16+l16, n-run = 16*(wn*4+j)+quad*4+r.
        // LDS-transposed epilogue: two 64-row passes; writers = waves wm==p;
        // then 256 threads store full-line 16B runs (wave covers 16 rows x
        // 128B). smem_ep rows padded to 136 elems (272B) to spread banks.
        bf16_t* QKout = (which == 0) ? Qb : Kb;
#pragma unroll
        for (int p = 0; p < 2; ++p) {
            __syncthreads();
            if (wm == p) {
#pragma unroll
                for (int j = 0; j < 4; ++j) {
                    const int u = wn * 4 + j;              // 16-col unit (0..7)
                    const f32x4 b4 = *reinterpret_cast<const f32x4*>(&bias[nrel0 + u * 16 + quad * 4]);
#pragma unroll
                    for (int i = 0; i < 4; ++i) {
                        bf16x4 pk;
#pragma unroll
                        for (int r = 0; r < 4; ++r) pk[r] = (bf16_t)((acc[i][j][r] + b4[r]) * oscale);
                        *reinterpret_cast<bf16x4*>(smem + (i * 16 + l16) * 136 + u * 16 + quad * 4) = pk;
                    }
                }
            }
            __syncthreads();
            const int row = tid >> 2, g = tid & 3;
            const int m = m0 + p * 64 + row;
            if (m < M_) {
                const int b = m / S_, s = m - b * S_;
                const int bh0 = b * NH_ + (nrel0 >> 6);
#pragma unroll
                for (int pc = 0; pc < 4; ++pc) {
                    const int e = (g + pc * 4) * 8;        // elem col 0..120
                    const int h = e >> 6, dd = e & 63;
                    bf16x8 v = *reinterpret_cast<const bf16x8*>(smem + row * 136 + e);
                    *reinterpret_cast<bf16x8*>(QKout + ((size_t)(bh0 + h) * S_ + s) * DH_ + dd) = v;
                }
            }
        }
    } else {
        GEMM_MAINLOOP(0)
        // normal: d from l16, s-run = m0+wm*64+i*16+quad*4+r
#pragma unroll
        for (int j = 0; j < 4; ++j) {
            const int nrel = nrel0 + wn * 64 + j * 16 + l16;
            const float bv_ = bias[nrel];
            const int h = nrel >> 6, d = nrel & 63;
#pragma unroll
            for (int i = 0; i < 4; ++i) {
                const int m = m0 + wm * 64 + i * 16 + quad * 4;
                const int b = m / S_, s = m - b * S_;
                if (m + 3 < M_ && s <= S_ - 4) {       // 4-run stays in one batch row
                    bf16x4 pk;
#pragma unroll
                    for (int r = 0; r < 4; ++r) pk[r] = (bf16_t)(acc[i][j][r] + bv_);
                    *reinterpret_cast<bf16x4*>(VTb + ((size_t)(b * NH_ + h) * DH_ + d) * SP + s) = pk;
                } else {
#pragma unroll
                    for (int r = 0; r < 4; ++r) {
                        const int mm = m + r;
                        if (mm >= M_) continue;
                        const int bb = mm / S_, ss = mm - bb * S_;
                        VTb[((size_t)(bb * NH_ + h) * DH_ + d) * SP + ss] = (bf16_t)(acc[i][j][r] + bv_);
                    }
                }
            }
        }
    }
}

// ---------------- flash attention: 4 q-tiles (64 rows) per wave (R14) ----------------
__global__ __launch_bounds__(256, 2) void flash_attn(
    const bf16_t* __restrict__ Qb, const bf16_t* __restrict__ Kb,
    const bf16_t* __restrict__ VTb, const float* __restrict__ maskp,
    bf16_t* __restrict__ Ctx)
{
    __shared__ __align__(16) float smask[SP];       // 2432B, zero-padded tail
    const int tid  = threadIdx.x;
    const int w    = tid >> 6, lane = tid & 63;
    const int quad = lane >> 4, l16 = lane & 15;

    const int bid  = blockIdx.x;
    const int work = (bid & 7) * 192 + (bid >> 3);  // bijective (1536%8==0)
    const int bh   = work / 3;
    const int qx   = work - bh * 3;
    const int b    = bh >> 4, h = bh & 15;

    for (int i = tid; i < SP; i += 256)
        smask[i] = (i < S_) ? maskp[b * S_ + i] : 0.f;
    __syncthreads();

    int idx = qx * 4 + w; if (idx > 9) idx = 9;     // dup work, same values
    const int q0 = idx * 64;

    const bf16_t* Qh = Qb  + (size_t)bh * S_ * DH_;
    const bf16_t* Kh = Kb  + (size_t)bh * S_ * DH_;
    const bf16_t* Vh = VTb + (size_t)bh * DH_ * SP;

    bf16x8 aq[4][2];
#pragma unroll
    for (int t = 0; t < 4; ++t) {
        int rq = q0 + t * 16 + l16; if (rq > S_ - 1) rq = S_ - 1;
        aq[t][0] = load8(Qh + rq * DH_ + quad * 8);
        aq[t][1] = load8(Qh + rq * DH_ + 32 + quad * 8);
    }

    const int g0 = ((l16 >> 2) << 3) + (l16 & 3);   // permuted K row (zero-shuffle)
    const int g1 = g0 + 4;

    f32x4 o[4][4] = {};                              // [q-tile][d-block]
    float lp[4] = {0.f, 0.f, 0.f, 0.f};

    bf16x8 ka[4], kb_[4];
    {
        int r0 = g0; if (r0 > S_ - 1) r0 = S_ - 1;
        int r1 = g1; if (r1 > S_ - 1) r1 = S_ - 1;
        ka[0] = load8(Kh + r0 * DH_ + quad * 8);
        ka[1] = load8(Kh + r0 * DH_ + 32 + quad * 8);
        ka[2] = load8(Kh + r1 * DH_ + quad * 8);
        ka[3] = load8(Kh + r1 * DH_ + 32 + quad * 8);
    }

    auto body = [&](bf16x8 (&KC)[4], bf16x8 (&KN)[4], const int j0, const bool pf) {
        // V for this tile + K for next: issue before the compute chain.
        bf16x8 v0 = load8(Vh + (l16)      * SP + j0 + quad * 8);
        bf16x8 v1 = load8(Vh + (16 + l16) * SP + j0 + quad * 8);
        bf16x8 v2 = load8(Vh + (32 + l16) * SP + j0 + quad * 8);
        bf16x8 v3 = load8(Vh + (48 + l16) * SP + j0 + quad * 8);
        if (pf) {
            int r0 = j0 + 32 + g0; if (r0 > S_ - 1) r0 = S_ - 1;
            int r1 = j0 + 32 + g1; if (r1 > S_ - 1) r1 = S_ - 1;
            KN[0] = load8(Kh + r0 * DH_ + quad * 8);
            KN[1] = load8(Kh + r0 * DH_ + 32 + quad * 8);
            KN[2] = load8(Kh + r1 * DH_ + quad * 8);
            KN[3] = load8(Kh + r1 * DH_ + 32 + quad * 8);
        }
        // scores for 4 q-tiles sharing KC: s0[t][r]=S[q][j0+8q+r], s1: +4
        f32x4 s0[4], s1[4];
        __builtin_amdgcn_s_setprio(1);
#pragma unroll
        for (int t = 0; t < 4; ++t) {
            f32x4 z0 = {}, z1 = {};
            z0 = MFMA_BF16(KC[0], aq[t][0], z0, 0, 0, 0);
            z0 = MFMA_BF16(KC[1], aq[t][1], z0, 0, 0, 0);
            z1 = MFMA_BF16(KC[2], aq[t][0], z1, 0, 0, 0);
            z1 = MFMA_BF16(KC[3], aq[t][1], z1, 0, 0, 0);
            s0[t] = z0; s1[t] = z1;
        }
        __builtin_amdgcn_s_setprio(0);

        const f32x4 mk0 = *reinterpret_cast<const f32x4*>(&smask[j0 + quad * 8]);
        const f32x4 mk1 = *reinterpret_cast<const f32x4*>(&smask[j0 + quad * 8 + 4]);
        bf16x8 ap[4];
#pragma unroll
        for (int t = 0; t < 4; ++t) {
#pragma unroll
            for (int r = 0; r < 4; ++r) {
                const int c0 = j0 + quad * 8 + r;
                const int c1 = c0 + 4;
                const float e0 = (c0 < S_) ? __expf(s0[t][r] * mk0[r]) : 0.f;
                const float e1 = (c1 < S_) ? __expf(s1[t][r] * mk1[r]) : 0.f;
                lp[t] += e0 + e1;           // P=0 on pad cols kills V poison
                ap[t][r] = (bf16_t)e0; ap[t][r + 4] = (bf16_t)e1;
            }
        }
        __builtin_amdgcn_s_setprio(1);
#pragma unroll
        for (int t = 0; t < 4; ++t) {
            o[t][0] = MFMA_BF16(ap[t], v0, o[t][0], 0, 0, 0);
            o[t][1] = MFMA_BF16(ap[t], v1, o[t][1], 0, 0, 0);
            o[t][2] = MFMA_BF16(ap[t], v2, o[t][2], 0, 0, 0);
            o[t][3] = MFMA_BF16(ap[t], v3, o[t][3], 0, 0, 0);
        }
        __builtin_amdgcn_s_setprio(0);
    };

    for (int j0 = 0; j0 < S_; j0 += 64) {           // 19 bodies, ka/kb alternate
        body(ka, kb_, j0, j0 + 32 < S_);
        if (j0 + 32 < S_) body(kb_, ka, j0 + 32, j0 + 64 < S_);
    }

    // row sums: quads hold disjoint k-slices of row q=l16 -> reduce over quads
    float liv[4][4];
#pragma unroll
    for (int t = 0; t < 4; ++t) {
        float ls = lp[t];
        ls += __shfl_xor(ls, 16); ls += __shfl_xor(ls, 32);
#pragma unroll
        for (int r = 0; r < 4; ++r)
            liv[t][r] = 1.0f / __shfl(ls, quad * 4 + r);   // lanes 0..15 full sums
    }

#pragma unroll
    for (int t = 0; t < 4; ++t) {
#pragma unroll
        for (int dt = 0; dt < 4; ++dt) {
#pragma unroll
            for (int r = 0; r < 4; ++r) {
                const int s = q0 + t * 16 + quad * 4 + r;
                if (s < S_)
                    Ctx[((size_t)(b * S_ + s) * NH_ + h) * DH_ + dt * 16 + l16] =
                        (bf16_t)(o[t][dt][r] * liv[t][r]);
            }
        }
    }
}

// ---------------- output projection (R9 1-phase, slab-12) ----------------
// 1-D grid 1160 = 145 m-tiles x 8 n-tiles.
__global__ __launch_bounds__(256) void out_gemm(
    const bf16_t* __restrict__ Ctx, const bf16_t* __restrict__ Wob,
    const float* __restrict__ bo, float* __restrict__ Out)
{
    __shared__ bf16_t smem[8192];
    bf16_t* sA = smem;
    bf16_t* sB = smem + 4096;
    const int tid  = threadIdx.x;
    const int w    = tid >> 6, lane = tid & 63;
    const int quad = lane >> 4, l16 = lane & 15;
    const int wm = w & 1, wn = w >> 1;

    const int t    = (blockIdx.x & 7) * 145 + (blockIdx.x >> 3);  // 1160%8==0
    const int slab = t / 96;                                      // 12 m x 8 n = 96
    const int rem  = t - slab * 96;
    int mt, nt;
    if (slab < 12) { nt = rem / 12; mt = slab * 12 + (rem - nt * 12); }
    else           { nt = rem;      mt = 144; }
    const int m0 = mt * 128, n0 = nt * 128;

    const int f0 = tid, f1 = 256 + tid;
    const int rA0 = f0 >> 2, cA0 = (f0 & 3) * 8;
    const int rA1 = f1 >> 2, cA1 = (f1 & 3) * 8;
    int ga0 = m0 + rA0; if (ga0 > M_ - 1) ga0 = M_ - 1;
    int ga1 = m0 + rA1; if (ga1 > M_ - 1) ga1 = M_ - 1;
    const bf16_t* pA0 = Ctx + (size_t)ga0 * H_ + cA0;
    const bf16_t* pA1 = Ctx + (size_t)ga1 * H_ + cA1;
    const bf16_t* pB0 = Wob + (size_t)(n0 + rA0) * H_ + cA0;
    const bf16_t* pB1 = Wob + (size_t)(n0 + rA1) * H_ + cA1;
    bf16_t* lA0 = sA + w * 512;
    bf16_t* lA1 = sA + 2048 + w * 512;
    bf16_t* lB0 = sB + w * 512;
    bf16_t* lB1 = sB + 2048 + w * 512;

    f32x4 acc[4][4] = {};
    GEMM_MAINLOOP(1)

    // swapped: m = m0+wm*64+i*16+l16, n-run = n0+wn*64+j*16+quad*4+{0..3}
#pragma unroll
    for (int j = 0; j < 4; ++j) {
        const int nb = n0 + wn * 64 + j * 16 + quad * 4;
        const f32x4 b4 = *reinterpret_cast<const f32x4*>(&bo[nb]);
#pragma unroll
        for (int i = 0; i < 4; ++i) {
            const int m = m0 + wm * 64 + i * 16 + l16;
            if (m >= M_) continue;
            f32x4 v = acc[i][j] + b4;
            *reinterpret_cast<f32x4*>(Out + (size_t)m * H_ + nb) = v;
        }
    }
}

extern "C" void kernel_launch(void* const* d_in, const int* in_sizes, int n_in,
                              void* d_out, int out_size, void* d_ws, size_t ws_size,
                              hipStream_t stream) {
    const float* hidden = (const float*)d_in[0];
    const float* mask   = (const float*)d_in[1];
    const float* Wq = (const float*)d_in[2];
    const float* bq = (const float*)d_in[3];
    const float* Wk = (const float*)d_in[4];
    const float* bk = (const float*)d_in[5];
    const float* Wv = (const float*)d_in[6];
    const float* bv = (const float*)d_in[7];
    const float* Wo = (const float*)d_in[8];
    const float* bo = (const float*)d_in[9];
    float* out = (float*)d_out;

    const size_t QK_EL = (size_t)B_ * NH_ * S_ * DH_;   // 18,907,136
    const size_t VT_EL = (size_t)B_ * NH_ * SP * DH_;   // 19,922,944
    const size_t X_EL  = (size_t)M_ * H_;               // 18,907,136
    const size_t W_EL  = (size_t)H_ * H_;               // 1,048,576
    const size_t NEED  = (2 * QK_EL + VT_EL + X_EL + 4 * W_EL) * sizeof(bf16_t); // ~161.7 MB
    if (ws_size < NEED) {
        hipMemsetAsync(d_out, 0, (size_t)out_size * sizeof(float), stream);
        return;
    }

    bf16_t* ws    = (bf16_t*)d_ws;
    bf16_t* Qb    = ws;
    bf16_t* Kb    = Qb + QK_EL;
    bf16_t* VTb   = Kb + QK_EL;
    bf16_t* XbCtx = VTb + VT_EL;      // X_bf16 during qkv; Ctx afterwards
    bf16_t* Wqb   = XbCtx + X_EL;
    bf16_t* Wkb   = Wqb + W_EL;
    bf16_t* Wvb   = Wkb + W_EL;
    bf16_t* Wob   = Wvb + W_EL;

    cvt_all<<<2048, 256, 0, stream>>>(hidden, Wq, Wk, Wv, Wo, XbCtx, Wqb, (int)(X_EL / 8));

    qkv_gemm<<<dim3(3480), dim3(256), 0, stream>>>(XbCtx, Wqb, Wkb, Wvb, bq, bk, bv, Qb, Kb, VTb);

    flash_attn<<<dim3(1536), dim3(256), 0, stream>>>(Qb, Kb, VTb, mask, XbCtx);  // Ctx aliases Xb

    out_gemm<<<dim3(1160), dim3(256), 0, stream>>>(XbCtx, Wob, bo, out);
}